// Round 1
// baseline (67.257 us; speedup 1.0000x reference)
//
#include <hip/hip_runtime.h>
#include <cstddef>

#define POOL 7
#define NEGV (-3e38f)
#define CG   32   // channels per block
#define CSUB 4    // channels processed per inner iteration (256 thr / 64 lanes)

__global__ __launch_bounds__(256) void roi_pool_kernel(
    const float* __restrict__ feat, const float* __restrict__ rois,
    float* __restrict__ out,
    int B, int C, int H, int W, int R)
{
    const int nCG = C / CG;
    const int bid = blockIdx.x;
    const int cgrp = bid % nCG;
    const int br   = bid / nCG;
    const int b = br / R;
    const int r = br % R;

    const int tid  = threadIdx.x;
    const int lane = tid & 63;
    const int csub = tid >> 6;   // 0..3

    // ---- decode ROI (same for all threads in block) ----
    const float* rp = rois + (size_t)(b * R + r) * 4;
    const int px = __float2int_rn(rp[0] * 0.0625f);
    const int py = __float2int_rn(rp[1] * 0.0625f);
    const int qx = __float2int_rn(rp[2] * 0.0625f);
    const int qy = __float2int_rn(rp[3] * 0.0625f);
    const int roi_w = max(qx - px + 1, 1);
    const int roi_h = max(qy - py + 1, 1);
    const int psw = (roi_w + POOL - 1) / POOL;
    const int psh = (roi_h + POOL - 1) / POOL;
    const int pad_l = (psw * POOL - roi_w) >> 1;
    const int pad_t = (psh * POOL - roi_h) >> 1;

    // clamped x for this lane (duplicates for lane >= roi_w are never read back)
    const int xg = px + min(lane, roi_w - 1);

    __shared__ float lds[CSUB][POOL][65];   // stride 65 breaks bank aliasing

    for (int cc = 0; cc < CG / CSUB; ++cc) {
        const int c = cgrp * CG + cc * CSUB + csub;
        const float* fp = feat + ((size_t)(b * C + c) * H) * W;

        // ---- phase 1: per-lane column maxes for the 7 pooled rows ----
#pragma unroll
        for (int i = 0; i < POOL; ++i) {
            const int ys = max(i * psh - pad_t, 0);
            const int ye = min((i + 1) * psh - pad_t, roi_h) - 1;
            float m = NEGV;
            for (int y = ys; y <= ye; ++y) {
                m = fmaxf(m, fp[(py + y) * W + xg]);
            }
            lds[csub][i][lane] = m;
        }
        __syncthreads();

        // ---- phase 2: reduce along x, apply pad rule, write out ----
        if (tid < CSUB * POOL * POOL) {
            const int cs2 = tid / 49;
            const int ij  = tid % 49;
            const int i   = ij / 7;
            const int j   = ij % 7;
            const int xs = max(j * psw - pad_l, 0);
            const int xe = min((j + 1) * psw - pad_l, roi_w) - 1;
            float m = NEGV;
            for (int x = xs; x <= xe; ++x) m = fmaxf(m, lds[cs2][i][x]);
            const bool padr = (i * psh < pad_t) || ((i + 1) * psh > pad_t + roi_h);
            const bool padc = (j * psw < pad_l) || ((j + 1) * psw > pad_l + roi_w);
            if (padr || padc) m = fmaxf(m, 0.0f);
            const int c2 = cgrp * CG + cc * CSUB + cs2;
            out[((size_t)(b * R + r) * C + c2) * 49 + ij] = m;
        }
        __syncthreads();
    }
}

extern "C" void kernel_launch(void* const* d_in, const int* in_sizes, int n_in,
                              void* d_out, int out_size, void* d_ws, size_t ws_size,
                              hipStream_t stream) {
    const float* feat = (const float*)d_in[0];
    const float* rois = (const float*)d_in[1];
    float* out = (float*)d_out;

    const int B = 2, C = 256, H = 64, W = 64, R = 64;
    const int blocks = B * R * (C / CG);
    roi_pool_kernel<<<blocks, 256, 0, stream>>>(feat, rois, out, B, C, H, W, R);
}

// Round 2
// 31.785 us; speedup vs baseline: 2.1160x; 2.1160x over previous
//
#include <hip/hip_runtime.h>
#include <cstddef>

#define POOL 7
#define NEGV (-3e38f)

// Column max over pooled row i's y-window, statically unrolled to KL
// mask-predicated loads (addresses clamped in-bounds, validity via select).
template<int KL>
__device__ __forceinline__ void col_max(const float* __restrict__ fp, int py, int psh,
                                        int pad_t, int roi_h, int xg, float (&acc)[POOL]) {
#pragma unroll
    for (int i = 0; i < POOL; ++i) {
        const int lo = max(i * psh - pad_t, 0);
        const int hi = min((i + 1) * psh - pad_t, roi_h) - 1;
        const int ys = py + lo;
        const int ye = py + hi;
        float m = NEGV;
#pragma unroll
        for (int k = 0; k < KL; ++k) {
            const int y = ys + k;
            const float v = fp[(min(y, 63) << 6) + xg];  // W == 64
            m = fmaxf(m, (y <= ye) ? v : NEGV);
        }
        acc[i] = m;
    }
}

template<int KL>
__device__ __forceinline__ float row_max(const float* __restrict__ rowp, int xs, int xe) {
    float m = NEGV;
#pragma unroll
    for (int k = 0; k < KL; ++k) {
        const int x = xs + k;
        const float v = rowp[min(x, 63)];
        m = fmaxf(m, (x <= xe) ? v : NEGV);
    }
    return m;
}

__global__ __launch_bounds__(256) void roi_pool_kernel(
    const float* __restrict__ feat, const float* __restrict__ rois,
    float* __restrict__ out)
{
    constexpr int C = 256, H = 64, W = 64, R = 64;
    const int tid  = threadIdx.x;
    const int lane = tid & 63;
    const int wv   = tid >> 6;                 // wave id in block (0..3)
    const int task = (blockIdx.x << 2) + wv;   // task = (b*R + r)*C + c
    const int c  = task & (C - 1);
    const int br = task >> 8;                  // b*R + r
    const int b  = br >> 6;

    // ---- decode ROI (wave-uniform) ----
    const float* rp = rois + (size_t)br * 4;
    const int px = __float2int_rn(rp[0] * 0.0625f);
    const int py = __float2int_rn(rp[1] * 0.0625f);
    const int qx = __float2int_rn(rp[2] * 0.0625f);
    const int qy = __float2int_rn(rp[3] * 0.0625f);
    const int roi_w = max(qx - px + 1, 1);
    const int roi_h = max(qy - py + 1, 1);
    const int psw = (roi_w + POOL - 1) / POOL;
    const int psh = (roi_h + POOL - 1) / POOL;
    const int pad_l = (psw * POOL - roi_w) >> 1;
    const int pad_t = (psh * POOL - roi_h) >> 1;

    // lane -> x column of the ROI (clamped duplicates never read back)
    const int xg = px + min(lane, roi_w - 1);
    const float* fp = feat + ((size_t)(b * C + c) << 12);   // H*W = 4096

    // ---- phase 1: per-lane column maxes, tiered static unroll on psh ----
    float acc[POOL];
    if      (psh <= 2) col_max<2 >(fp, py, psh, pad_t, roi_h, xg, acc);
    else if (psh <= 4) col_max<4 >(fp, py, psh, pad_t, roi_h, xg, acc);
    else if (psh <= 6) col_max<6 >(fp, py, psh, pad_t, roi_h, xg, acc);
    else               col_max<10>(fp, py, psh, pad_t, roi_h, xg, acc);

    // ---- wave-synchronous LDS handoff (no __syncthreads: same wave writes & reads) ----
    __shared__ float lds[4][POOL][65];
#pragma unroll
    for (int i = 0; i < POOL; ++i) lds[wv][i][lane] = acc[i];

    // ---- phase 2: reduce along x, apply pad rule, write out ----
    if (lane < POOL * POOL) {
        const int i = lane / POOL;
        const int j = lane % POOL;
        const int lo = max(j * psw - pad_l, 0);
        const int hi = min((j + 1) * psw - pad_l, roi_w) - 1;
        const float* rowp = lds[wv][i];
        float m;
        if      (psw <= 2) m = row_max<2 >(rowp, lo, hi);
        else if (psw <= 4) m = row_max<4 >(rowp, lo, hi);
        else if (psw <= 6) m = row_max<6 >(rowp, lo, hi);
        else               m = row_max<10>(rowp, lo, hi);
        const bool padr = (i * psh < pad_t) | ((i + 1) * psh > pad_t + roi_h);
        const bool padc = (j * psw < pad_l) | ((j + 1) * psw > pad_l + roi_w);
        if (padr | padc) m = fmaxf(m, 0.0f);
        out[(size_t)task * 49 + lane] = m;
    }
}

extern "C" void kernel_launch(void* const* d_in, const int* in_sizes, int n_in,
                              void* d_out, int out_size, void* d_ws, size_t ws_size,
                              hipStream_t stream) {
    const float* feat = (const float*)d_in[0];
    const float* rois = (const float*)d_in[1];
    float* out = (float*)d_out;

    const int B = 2, C = 256, R = 64;
    const int tasks = B * R * C;               // 32768 waves
    roi_pool_kernel<<<tasks / 4, 256, 0, stream>>>(feat, rois, out);
}

// Round 3
// 23.327 us; speedup vs baseline: 2.8832x; 1.3626x over previous
//
#include <hip/hip_runtime.h>
#include <cstddef>

#define POOL 7
#define NEGV (-3e38f)

__device__ __forceinline__ float4 fmax4(float4 a, float4 b) {
    return make_float4(fmaxf(a.x, b.x), fmaxf(a.y, b.y),
                       fmaxf(a.z, b.z), fmaxf(a.w, b.w));
}

// Column maxes (4 columns per lane) for the 7 pooled rows. Masked-out k steps
// re-load the last valid row (max-idempotent) instead of per-lane selects;
// empty windows get a wave-uniform kill afterwards.
template<int KL>
__device__ __forceinline__ void col_max4(const float4* __restrict__ fp4, int py, int psh,
                                         int pad_t, int roi_h, int xq, float4 (&acc)[POOL]) {
#pragma unroll
    for (int i = 0; i < POOL; ++i) {
        const int lo = max(i * psh - pad_t, 0);
        const int hi = min((i + 1) * psh - pad_t, roi_h) - 1;
        const int ys = py + lo;
        const int ye = py + hi;
        const int yc = min(max(ye, ys), 63);   // clamp target (empty-safe, in-bounds)
        float4 m = make_float4(NEGV, NEGV, NEGV, NEGV);
#pragma unroll
        for (int k = 0; k < KL; ++k) {
            const int y = min(ys + k, yc);
            m = fmax4(m, fp4[(y << 4) + xq]);
        }
        if (lo > hi) m = make_float4(NEGV, NEGV, NEGV, NEGV);  // empty y-window
        acc[i] = m;
    }
}

__global__ __launch_bounds__(256) void roi_pool_kernel(
    const float* __restrict__ feat, const float* __restrict__ rois,
    float* __restrict__ out)
{
    const int tid  = threadIdx.x;
    const int lane = tid & 63;
    const int wv   = tid >> 6;
    const int br   = blockIdx.x >> 4;                       // b*64 + r (block-uniform)
    const int b    = br >> 6;
    const int c0   = ((blockIdx.x & 15) << 4) + (wv << 2);  // wave's first channel
    const int cs   = lane >> 4;                             // channel slot 0..3
    const int lx   = lane & 15;                             // quad lane 0..15

    // ---- ROI decode (block-uniform -> scalar loads) ----
    const float* rp = rois + (size_t)br * 4;
    const int px = __float2int_rn(rp[0] * 0.0625f);
    const int py = __float2int_rn(rp[1] * 0.0625f);
    const int qx = __float2int_rn(rp[2] * 0.0625f);
    const int qy = __float2int_rn(rp[3] * 0.0625f);
    const int roi_w = max(qx - px + 1, 1);
    const int roi_h = max(qy - py + 1, 1);
    const int psw = (roi_w + POOL - 1) / POOL;
    const int psh = (roi_h + POOL - 1) / POOL;
    const int pad_l = (psw * POOL - roi_w) >> 1;
    const int pad_t = (psh * POOL - roi_h) >> 1;

    // quad coverage of [px, qx]; clamped duplicates touch the same cachelines
    const int qbase = px >> 2;
    const int nq    = (qx >> 2) - qbase + 1;
    const int Lq    = min(lx, nq - 1);
    const int xq    = qbase + Lq;

    const int c = c0 + cs;
    const float4* fp4 = (const float4*)feat + ((size_t)((b << 8) + c) << 10);  // H*W/4 = 1024

    // ---- phase 1: all loads up front, tiered static unroll on psh ----
    float4 acc[POOL];
    if      (psh <= 2) col_max4<2 >(fp4, py, psh, pad_t, roi_h, xq, acc);
    else if (psh <= 4) col_max4<4 >(fp4, py, psh, pad_t, roi_h, xq, acc);
    else if (psh <= 6) col_max4<6 >(fp4, py, psh, pad_t, roi_h, xq, acc);
    else               col_max4<10>(fp4, py, psh, pad_t, roi_h, xq, acc);

    __shared__ __attribute__((aligned(16))) float lds[4][2][4][64];  // [wave][parity][cs][x]

    // ---- phase 2 per-lane setup (lane < 28 active: i7 = channel slot, j7 = pooled col) ----
    const int i7  = lane / 7;
    const int j7  = lane - i7 * 7;
    const int pxl = px & 3;                        // px offset within its quad
    const int lox = max(j7 * psw - pad_l, 0);
    const int hix = min((j7 + 1) * psw - pad_l, roi_w) - 1;
    const int xs  = pxl + lox;                     // local col range [xs, xe]
    const int xe  = pxl + hix;                     // xe <= 63; may be < xs (empty)
    const int qs  = xs >> 2;
    const int qe  = xe >> 2;                       // may be < qs or negative
    const bool padc = (j7 * psw < pad_l) | ((j7 + 1) * psw > pad_l + roi_w);
    const size_t obase = ((size_t)(br << 8) + c0 + i7) * 49 + j7;

#pragma unroll
    for (int i = 0; i < POOL; ++i) {
        // write row i column-maxes (wave-in-order DS pipe: no barrier needed)
        float* wrow = &lds[wv][i & 1][cs][0];
        *(float4*)(wrow + (Lq << 2)) = acc[i];
        if (lane < 28) {
            const float* rrow = &lds[wv][i & 1][i7][0];
            float m = NEGV;
#pragma unroll
            for (int t = 0; t < 4; ++t) {
                const int q = max(min(qs + t, qe), 0);   // clamp (dup reads broadcast)
                const float4 v = *(const float4*)(rrow + (q << 2));
                const int cb = q << 2;
                m = fmaxf(m, (cb     >= xs && cb     <= xe) ? v.x : NEGV);
                m = fmaxf(m, (cb + 1 >= xs && cb + 1 <= xe) ? v.y : NEGV);
                m = fmaxf(m, (cb + 2 >= xs && cb + 2 <= xe) ? v.z : NEGV);
                m = fmaxf(m, (cb + 3 >= xs && cb + 3 <= xe) ? v.w : NEGV);
            }
            const bool padr = (i * psh < pad_t) | ((i + 1) * psh > pad_t + roi_h);
            if (padr | padc) m = fmaxf(m, 0.0f);
            out[obase + (size_t)i * 7] = m;
        }
    }
}

extern "C" void kernel_launch(void* const* d_in, const int* in_sizes, int n_in,
                              void* d_out, int out_size, void* d_ws, size_t ws_size,
                              hipStream_t stream) {
    const float* feat = (const float*)d_in[0];
    const float* rois = (const float*)d_in[1];
    float* out = (float*)d_out;

    // tasks = 2*64*256 channels; 4 channels per wave, 4 waves per block
    const int blocks = 2 * 64 * 256 / 16;   // 2048
    roi_pool_kernel<<<blocks, 256, 0, stream>>>(feat, rois, out);
}

// Round 4
// 18.177 us; speedup vs baseline: 3.7001x; 1.2833x over previous
//
#include <hip/hip_runtime.h>
#include <cstddef>

#define POOL 7
#define NEGV (-3e38f)

__device__ __forceinline__ float4 fmax4(float4 a, float4 b) {
    return make_float4(fmaxf(a.x, b.x), fmaxf(a.y, b.y),
                       fmaxf(a.z, b.z), fmaxf(a.w, b.w));
}

// Phase 1: per-lane column maxes (4 columns = 1 quad) for the 7 pooled rows.
// All of py/psh/pad_t/roi_h are SGPR-uniform -> the y chain is SALU and each
// load is global_load(vgpr_quad_offset, sgpr_row_base). Clamped re-loads of
// the last valid row are max-idempotent; empty windows killed afterwards.
template<int KL>
__device__ __forceinline__ void col_max4(const float4* __restrict__ fp4,
        int py, int psh, int pad_t, int roi_h, int xq, float4 (&acc)[POOL]) {
#pragma unroll
    for (int i = 0; i < POOL; ++i) {
        const int lo = max(i * psh - pad_t, 0);
        const int hi = min((i + 1) * psh - pad_t, roi_h) - 1;
        const int ys = py + lo;
        const int yc = min(py + max(hi, lo), 63);   // empty-safe, in-bounds
        float4 m = make_float4(NEGV, NEGV, NEGV, NEGV);
#pragma unroll
        for (int k = 0; k < KL; ++k) {
            const int y = min(ys + k, yc);          // scalar
            m = fmax4(m, fp4[(y << 4) + xq]);
        }
        if (lo > hi) m = make_float4(NEGV, NEGV, NEGV, NEGV);
        acc[i] = m;
    }
}

// Phase 2: interleaved LDS handoff (parity double-buffer, wave-in-order DS
// pipe => no barriers) + exact scalar clamped reads: KW >= window width,
// x = min(xs+k, xec) stays in [0,63] and re-reads are max-idempotent.
template<int KW>
__device__ __forceinline__ void phase2_run(const float4 (&acc)[POOL],
        float* ldsbase, int Lq, int cs, bool active, int i7, int j7,
        int xs, int xec, bool xempty, bool padc,
        int psh, int pad_t, int roi_h,
        float* __restrict__ out, size_t obase) {
#pragma unroll
    for (int i = 0; i < POOL; ++i) {
        float* wrow = ldsbase + (((i & 1) << 2) + cs) * 64;
        *(float4*)(wrow + (Lq << 2)) = acc[i];
        if (active) {
            const float* rrow = ldsbase + (((i & 1) << 2) + i7) * 64;
            float m = NEGV;
#pragma unroll
            for (int k = 0; k < KW; ++k) {
                m = fmaxf(m, rrow[min(xs + k, xec)]);
            }
            if (xempty) m = NEGV;
            const bool padr = (i * psh < pad_t) | ((i + 1) * psh > pad_t + roi_h);
            if (padr | padc) m = fmaxf(m, 0.0f);
            out[obase + (size_t)i * 7] = m;
        }
    }
}

__global__ __launch_bounds__(256) void roi_pool_kernel(
    const float* __restrict__ feat, const float* __restrict__ rois,
    float* __restrict__ out)
{
    const int tid  = threadIdx.x;
    const int lane = tid & 63;
    const int wv   = tid >> 6;
    const int br   = blockIdx.x >> 4;                       // b*64 + r (block-uniform)
    const int b    = br >> 6;
    const int c0   = ((blockIdx.x & 15) << 4) + (wv << 2);  // wave's first channel
    const int cs   = lane >> 4;                             // channel slot 0..3
    const int lx   = lane & 15;                             // quad slot 0..15

    // ---- ROI decode; force SGPR so everything downstream scalarizes ----
    const float* rp = rois + (size_t)br * 4;
    const int px = __builtin_amdgcn_readfirstlane(__float2int_rn(rp[0] * 0.0625f));
    const int py = __builtin_amdgcn_readfirstlane(__float2int_rn(rp[1] * 0.0625f));
    const int qx = __builtin_amdgcn_readfirstlane(__float2int_rn(rp[2] * 0.0625f));
    const int qy = __builtin_amdgcn_readfirstlane(__float2int_rn(rp[3] * 0.0625f));
    const int roi_w = max(qx - px + 1, 1);
    const int roi_h = max(qy - py + 1, 1);
    const int psw = (roi_w + POOL - 1) / POOL;
    const int psh = (roi_h + POOL - 1) / POOL;
    const int pad_l = (psw * POOL - roi_w) >> 1;
    const int pad_t = (psh * POOL - roi_h) >> 1;

    // quad coverage of [px,qx]; clamped duplicate lanes hit the same lines
    const int qbase = px >> 2;
    const int nq    = (qx >> 2) - qbase + 1;
    const int Lq    = min(lx, nq - 1);
    const int xq    = qbase + Lq;

    const int c = c0 + cs;
    const float4* fp4 = (const float4*)feat + ((size_t)((b << 8) + c) << 10);

    // ---- phase 1 (exact-ish tier ladder on psh) ----
    float4 acc[POOL];
    switch (psh) {
        case 1:  col_max4<1 >(fp4, py, psh, pad_t, roi_h, xq, acc); break;
        case 2:  col_max4<2 >(fp4, py, psh, pad_t, roi_h, xq, acc); break;
        case 3:  col_max4<3 >(fp4, py, psh, pad_t, roi_h, xq, acc); break;
        case 4:  col_max4<4 >(fp4, py, psh, pad_t, roi_h, xq, acc); break;
        case 5:  col_max4<5 >(fp4, py, psh, pad_t, roi_h, xq, acc); break;
        case 6:  col_max4<6 >(fp4, py, psh, pad_t, roi_h, xq, acc); break;
        case 7:
        case 8:  col_max4<8 >(fp4, py, psh, pad_t, roi_h, xq, acc); break;
        default: col_max4<10>(fp4, py, psh, pad_t, roi_h, xq, acc); break;
    }

    // ---- phase 2 per-lane setup (active lanes: i7 = channel slot, j7 = col) ----
    __shared__ __attribute__((aligned(16))) float lds[4][2][4][64];
    const bool active = lane < 28;
    const int i7  = lane / 7;
    const int j7  = lane - i7 * 7;
    const int pxl = px & 3;
    const int lox = max(j7 * psw - pad_l, 0);
    const int hix = min((j7 + 1) * psw - pad_l, roi_w) - 1;
    const int xs  = pxl + lox;                 // >= 0
    const int xe  = pxl + hix;                 // <= 63; < xs if empty
    const int xec = max(xe, 0);
    const bool xempty = xe < xs;
    const bool padc = (j7 * psw < pad_l) | ((j7 + 1) * psw > pad_l + roi_w);
    const size_t obase = ((size_t)(br << 8) + c0 + i7) * 49 + j7;
    float* ldsbase = &lds[wv][0][0][0];

    switch (psw) {
        case 1:  phase2_run<1 >(acc, ldsbase, Lq, cs, active, i7, j7, xs, xec, xempty, padc, psh, pad_t, roi_h, out, obase); break;
        case 2:  phase2_run<2 >(acc, ldsbase, Lq, cs, active, i7, j7, xs, xec, xempty, padc, psh, pad_t, roi_h, out, obase); break;
        case 3:  phase2_run<3 >(acc, ldsbase, Lq, cs, active, i7, j7, xs, xec, xempty, padc, psh, pad_t, roi_h, out, obase); break;
        case 4:  phase2_run<4 >(acc, ldsbase, Lq, cs, active, i7, j7, xs, xec, xempty, padc, psh, pad_t, roi_h, out, obase); break;
        case 5:  phase2_run<5 >(acc, ldsbase, Lq, cs, active, i7, j7, xs, xec, xempty, padc, psh, pad_t, roi_h, out, obase); break;
        case 6:  phase2_run<6 >(acc, ldsbase, Lq, cs, active, i7, j7, xs, xec, xempty, padc, psh, pad_t, roi_h, out, obase); break;
        case 7:
        case 8:  phase2_run<8 >(acc, ldsbase, Lq, cs, active, i7, j7, xs, xec, xempty, padc, psh, pad_t, roi_h, out, obase); break;
        default: phase2_run<10>(acc, ldsbase, Lq, cs, active, i7, j7, xs, xec, xempty, padc, psh, pad_t, roi_h, out, obase); break;
    }
}

extern "C" void kernel_launch(void* const* d_in, const int* in_sizes, int n_in,
                              void* d_out, int out_size, void* d_ws, size_t ws_size,
                              hipStream_t stream) {
    const float* feat = (const float*)d_in[0];
    const float* rois = (const float*)d_in[1];
    float* out = (float*)d_out;

    // 2*64 ROIs x 256 channels; 4 channels/wave, 4 waves/block -> 2048 blocks
    const int blocks = 2 * 64 * 256 / 16;
    roi_pool_kernel<<<blocks, 256, 0, stream>>>(feat, rois, out);
}

// Round 5
// 17.265 us; speedup vs baseline: 3.8956x; 1.0528x over previous
//
#include <hip/hip_runtime.h>
#include <cstddef>

#define POOL 7
#define NEGV (-3e38f)

__device__ __forceinline__ float4 fmax4(float4 a, float4 b) {
    return make_float4(fmaxf(a.x, b.x), fmaxf(a.y, b.y),
                       fmaxf(a.z, b.z), fmaxf(a.w, b.w));
}

// Phase 1: per-lane column maxes (1 quad = 4 columns) for the 7 pooled rows.
// Loads are batched into statically-indexed register arrays (<=6 in flight)
// BEFORE any fmax -> back-to-back global_load_dwordx4, one vmcnt wait per
// batch. y addresses are SGPR-uniform; clamped re-loads are max-idempotent.
template<int KL>
__device__ __forceinline__ void col_max4(const float4* __restrict__ fp4,
        int py, int psh, int pad_t, int roi_h, int xq, float4 (&acc)[POOL]) {
    constexpr int B1 = (KL <= 6) ? KL : (KL + 1) / 2;   // batch size (10->5, 8->4)
    constexpr int NB = (KL + B1 - 1) / B1;
#pragma unroll
    for (int i = 0; i < POOL; ++i) {
        const int lo = max(i * psh - pad_t, 0);
        const int hi = min((i + 1) * psh - pad_t, roi_h) - 1;
        const int ys = py + lo;
        const int yc = min(py + max(hi, lo), 63);       // empty-safe, in-bounds
        float4 m = make_float4(NEGV, NEGV, NEGV, NEGV);
#pragma unroll
        for (int bb = 0; bb < NB; ++bb) {
            float4 t[B1];
#pragma unroll
            for (int k = 0; k < B1; ++k) {
                const int y = min(ys + bb * B1 + k, yc);   // scalar chain
                t[k] = fp4[(y << 4) + xq];
            }
#pragma unroll
            for (int k = 0; k < B1; ++k) m = fmax4(m, t[k]);
        }
        if (lo > hi) m = make_float4(NEGV, NEGV, NEGV, NEGV);
        acc[i] = m;
    }
}

// Phase 2: parity-double-buffered LDS handoff (wave-in-order DS pipe, no
// barriers). Reads batched into registers -> one lgkm wait per pooled row.
template<int KW>
__device__ __forceinline__ void phase2_run(const float4 (&acc)[POOL],
        float* ldsbase, int Lq, int cs, bool active, int i7,
        int xs, int xec, bool xempty, bool padc,
        int psh, int pad_t, int roi_h,
        float* __restrict__ out, size_t obase) {
#pragma unroll
    for (int i = 0; i < POOL; ++i) {
        float* wrow = ldsbase + (((i & 1) << 2) + cs) * 64;
        *(float4*)(wrow + (Lq << 2)) = acc[i];
        if (active) {
            const float* rrow = ldsbase + (((i & 1) << 2) + i7) * 64;
            float t[KW];
#pragma unroll
            for (int k = 0; k < KW; ++k) t[k] = rrow[min(xs + k, xec)];
            float m = t[0];
#pragma unroll
            for (int k = 1; k < KW; ++k) m = fmaxf(m, t[k]);
            if (xempty) m = NEGV;
            const bool padr = (i * psh < pad_t) | ((i + 1) * psh > pad_t + roi_h);
            if (padr | padc) m = fmaxf(m, 0.0f);
            out[obase + (size_t)i * 7] = m;
        }
    }
}

__global__ __launch_bounds__(256) void roi_pool_kernel(
    const float* __restrict__ feat, const float* __restrict__ rois,
    float* __restrict__ out)
{
    const int tid  = threadIdx.x;
    const int lane = tid & 63;
    const int wv   = tid >> 6;
    const int br   = blockIdx.x >> 4;                       // b*64 + r (block-uniform)
    const int b    = br >> 6;
    const int c0   = ((blockIdx.x & 15) << 4) + (wv << 2);  // wave's first channel
    const int cs   = lane >> 4;                             // channel slot 0..3
    const int lx   = lane & 15;                             // quad slot 0..15

    // ---- ROI decode; force SGPR so downstream address math scalarizes ----
    const float* rp = rois + (size_t)br * 4;
    const int px = __builtin_amdgcn_readfirstlane(__float2int_rn(rp[0] * 0.0625f));
    const int py = __builtin_amdgcn_readfirstlane(__float2int_rn(rp[1] * 0.0625f));
    const int qx = __builtin_amdgcn_readfirstlane(__float2int_rn(rp[2] * 0.0625f));
    const int qy = __builtin_amdgcn_readfirstlane(__float2int_rn(rp[3] * 0.0625f));
    const int roi_w = max(qx - px + 1, 1);
    const int roi_h = max(qy - py + 1, 1);
    const int psw = (roi_w + POOL - 1) / POOL;
    const int psh = (roi_h + POOL - 1) / POOL;
    const int pad_l = (psw * POOL - roi_w) >> 1;
    const int pad_t = (psh * POOL - roi_h) >> 1;

    // quad coverage of [px,qx]; clamped duplicate lanes hit the same lines
    const int qbase = px >> 2;
    const int nq    = (qx >> 2) - qbase + 1;
    const int Lq    = min(lx, nq - 1);
    const int xq    = qbase + Lq;

    const int c = c0 + cs;
    const float4* fp4 = (const float4*)feat + ((size_t)((b << 8) + c) << 10);

    // ---- phase 1 (exact tier ladder on psh; big tiers split into 2 batches) ----
    float4 acc[POOL];
    switch (psh) {
        case 1:  col_max4<1 >(fp4, py, psh, pad_t, roi_h, xq, acc); break;
        case 2:  col_max4<2 >(fp4, py, psh, pad_t, roi_h, xq, acc); break;
        case 3:  col_max4<3 >(fp4, py, psh, pad_t, roi_h, xq, acc); break;
        case 4:  col_max4<4 >(fp4, py, psh, pad_t, roi_h, xq, acc); break;
        case 5:  col_max4<5 >(fp4, py, psh, pad_t, roi_h, xq, acc); break;
        case 6:  col_max4<6 >(fp4, py, psh, pad_t, roi_h, xq, acc); break;
        case 7:
        case 8:  col_max4<8 >(fp4, py, psh, pad_t, roi_h, xq, acc); break;
        default: col_max4<10>(fp4, py, psh, pad_t, roi_h, xq, acc); break;
    }

    // ---- phase 2 setup (active lanes: i7 = channel slot, j7 = pooled col) ----
    __shared__ __attribute__((aligned(16))) float lds[4][2][4][64];
    const bool active = lane < 28;
    const int i7  = lane / 7;
    const int j7  = lane - i7 * 7;
    const int pxl = px & 3;
    const int lox = max(j7 * psw - pad_l, 0);
    const int hix = min((j7 + 1) * psw - pad_l, roi_w) - 1;
    const int xs  = pxl + lox;                 // >= 0
    const int xe  = pxl + hix;                 // <= 63; < xs if empty
    const int xec = max(xe, 0);
    const bool xempty = xe < xs;
    const bool padc = (j7 * psw < pad_l) | ((j7 + 1) * psw > pad_l + roi_w);
    const size_t obase = ((size_t)(br << 8) + c0 + i7) * 49 + j7;
    float* ldsbase = &lds[wv][0][0][0];

    switch (psw) {
        case 1:  phase2_run<1 >(acc, ldsbase, Lq, cs, active, i7, xs, xec, xempty, padc, psh, pad_t, roi_h, out, obase); break;
        case 2:  phase2_run<2 >(acc, ldsbase, Lq, cs, active, i7, xs, xec, xempty, padc, psh, pad_t, roi_h, out, obase); break;
        case 3:  phase2_run<3 >(acc, ldsbase, Lq, cs, active, i7, xs, xec, xempty, padc, psh, pad_t, roi_h, out, obase); break;
        case 4:  phase2_run<4 >(acc, ldsbase, Lq, cs, active, i7, xs, xec, xempty, padc, psh, pad_t, roi_h, out, obase); break;
        case 5:  phase2_run<5 >(acc, ldsbase, Lq, cs, active, i7, xs, xec, xempty, padc, psh, pad_t, roi_h, out, obase); break;
        case 6:  phase2_run<6 >(acc, ldsbase, Lq, cs, active, i7, xs, xec, xempty, padc, psh, pad_t, roi_h, out, obase); break;
        case 7:
        case 8:  phase2_run<8 >(acc, ldsbase, Lq, cs, active, i7, xs, xec, xempty, padc, psh, pad_t, roi_h, out, obase); break;
        default: phase2_run<10>(acc, ldsbase, Lq, cs, active, i7, xs, xec, xempty, padc, psh, pad_t, roi_h, out, obase); break;
    }
}

extern "C" void kernel_launch(void* const* d_in, const int* in_sizes, int n_in,
                              void* d_out, int out_size, void* d_ws, size_t ws_size,
                              hipStream_t stream) {
    const float* feat = (const float*)d_in[0];
    const float* rois = (const float*)d_in[1];
    float* out = (float*)d_out;

    // 2*64 ROIs x 256 channels; 4 channels/wave, 4 waves/block -> 2048 blocks
    const int blocks = 2 * 64 * 256 / 16;
    roi_pool_kernel<<<blocks, 256, 0, stream>>>(feat, rois, out);
}